// Round 7
// baseline (3390.219 us; speedup 1.0000x reference)
//
#include <hip/hip_runtime.h>

typedef short short8 __attribute__((ext_vector_type(8)));
typedef float f32x4 __attribute__((ext_vector_type(4)));

#define XP_BYTES (16ull * 130 * 130 * 128 * 2)

static __device__ __forceinline__ unsigned short f2bf(float f) {
  unsigned u = __float_as_uint(f);
  u += 0x7FFFu + ((u >> 16) & 1u);
  return (unsigned short)(u >> 16);
}

static __device__ __forceinline__ void gload16(const void* g, void* l) {
  __builtin_amdgcn_global_load_lds(
      (const __attribute__((address_space(1))) void*)g,
      (__attribute__((address_space(3))) void*)l, 16, 0, 0);
}

// ---------------- weight rotation: (O*R,I,3,3) fp32 -> W2[n'=o*8+r][tap*128+ic] bf16
static __device__ __forceinline__ float wtap(const float* f, int yi, int xi) {
  bool valid = (yi >= 0) & (yi < 3) & (xi >= 0) & (xi < 3);
  int yc = min(max(yi, 0), 2), xc = min(max(xi, 0), 2);
  return valid ? f[yc * 3 + xc] : 0.f;
}

__global__ __launch_bounds__(256) void wprep_kernel(
    const float* __restrict__ w, const float* __restrict__ rot_alpha,
    unsigned short* __restrict__ w2) {
  int gid = blockIdx.x * 256 + threadIdx.x;  // 131072 = 1024 * 128
  int ic = gid & 127;
  int nr = gid >> 7;  // n' = o*8 + r
  int r = nr & 7;
  const float* wf = w + (size_t)nr * (128 * 9) + (size_t)ic * 9;
  float f[9];
#pragma unroll
  for (int q = 0; q < 9; ++q) f[q] = wf[q];
  float ang = rot_alpha[r] * 0.78539816339744830962f * (float)r;
  float sth, cth;
  sincosf(ang, &sth, &cth);
#pragma unroll
  for (int j = 0; j < 3; ++j) {
#pragma unroll
    for (int i = 0; i < 3; ++i) {
      float gy = (float)(j - 1), gx = (float)(i - 1);
      float xs = cth * gx - sth * gy;
      float ys = sth * gx + cth * gy;
      float ix = xs + 1.0f, iy = ys + 1.0f;
      float x0f = floorf(ix), y0f = floorf(iy);
      int x0 = (int)x0f, y0 = (int)y0f;
      float wx = ix - x0f, wy = iy - y0f;
      float acc = wtap(f, y0, x0) * (1.f - wy) * (1.f - wx)
                + wtap(f, y0, x0 + 1) * (1.f - wy) * wx
                + wtap(f, y0 + 1, x0) * wy * (1.f - wx)
                + wtap(f, y0 + 1, x0 + 1) * wy * wx;
      w2[(size_t)nr * 1152 + (size_t)(j * 3 + i) * 128 + ic] = f2bf(acc);
    }
  }
}

// ---------------- x: NCHW fp32 -> padded NHWC bf16 xp[16][130][130][128]
__global__ __launch_bounds__(256) void xprep_kernel(
    const float* __restrict__ x, unsigned short* __restrict__ xp) {
  const int yy = blockIdx.x;  // 0..129
  const int b = blockIdx.y;   // 0..15
  const int t = threadIdx.x;
  const size_t rowbase = ((size_t)b * 130 + yy) * (130 * 128);
  if (yy == 0 || yy == 129) {
    uint4 z = {0u, 0u, 0u, 0u};
    for (int i = t; i < 2080; i += 256)
      ((uint4*)(xp + rowbase))[i] = z;
    return;
  }
  const int y = yy - 1;
  __shared__ float lt[32][129];
  if (t < 32) {
    uint4 z = {0u, 0u, 0u, 0u};
    int xx = (t < 16) ? 0 : 129;
    int cc = (t & 15) * 8;
    *(uint4*)(xp + rowbase + (size_t)xx * 128 + cc) = z;
  }
  for (int c0 = 0; c0 < 128; c0 += 32) {
#pragma unroll
    for (int i = 0; i < 16; ++i) {
      int idx = i * 256 + t;
      int c = idx >> 7, wq = idx & 127;
      lt[c][wq] = x[(((size_t)b * 128 + c0 + c) * 128 + y) * 128 + wq];
    }
    __syncthreads();
#pragma unroll
    for (int i = 0; i < 2; ++i) {
      int u = i * 256 + t;
      int xx = u >> 2, cp = (u & 3) * 8;
      unsigned short v[8];
#pragma unroll
      for (int q = 0; q < 8; ++q) v[q] = f2bf(lt[cp + q][xx]);
      *(uint4*)(xp + rowbase + (size_t)(xx + 1) * 128 + c0 + cp) = *(uint4*)v;
    }
    __syncthreads();
  }
}

// ---------------- implicit-GEMM conv, 256x256 tile, BK=64, 8 waves.
// ANTI-PHASE wave groups (wv&1): per SIMD one wave reads LDS while its
// sibling runs MFMA on fragments pre-read one window earlier. 2 barriers
// per K-tile, vmcnt(4) before each (forces exactly the half-tile needed
// next window). Swizzled LDS (conflict-free), counted-vmcnt staging.
__global__ __launch_bounds__(512, 2) void conv_kernel(
    const unsigned short* __restrict__ xp,
    const unsigned short* __restrict__ w2,
    float* __restrict__ out) {
  __shared__ unsigned short lds[65536];  // 128 KiB

  const int tid = threadIdx.x;
  const int lane = tid & 63;
  const int wv = tid >> 6;  // 0..7
  const int wr = wv >> 2;   // M half
  const int wc = wv & 3;    // N quarter
  const int grp = wv & 1;   // anti-phase group

  const int bid = blockIdx.x;
  const int wg = (bid & 7) * 512 + (bid >> 3);  // XCD swizzle (4096 % 8 == 0)
  const int mblk = wg >> 2;
  const int nblk = wg & 3;
  const int b = mblk >> 6;
  const int y0 = (mblk & 63) << 1;

  // staging decode: thread t covers row r0, lds slot s0 (16B slots, 4/row)
  const int r0 = tid >> 2;
  const int s0 = tid & 3;
  const int g0 = s0 ^ ((r0 >> 1) & 3);  // global k-group (inverse swizzle)
  const int wvoff = wv * 512;           // shorts: wave's linear chunk base

  const unsigned short* xpt =
      xp + (size_t)(b * 130 + y0) * 130 * 128 + r0 * 128 + g0 * 8;
  const unsigned short* wpt =
      w2 + (size_t)nblk * 256 * 1152 + (size_t)r0 * 1152 + g0 * 8;

  const int l15 = lane & 15;
  const int lhi = lane >> 4;
  const int sa = (lhi ^ ((l15 >> 1) & 3)) * 8;  // read-side swizzled slot

  const int aRd = wr * 8192 + l15 * 32 + sa;                       // shorts
  const int bRd = 32768 + (wc >> 1) * 8192 + (wc & 1) * 2048 + l15 * 32 + sa;

  f32x4 acc[8][4];
#pragma unroll
  for (int mf = 0; mf < 8; ++mf)
#pragma unroll
    for (int nf = 0; nf < 4; ++nf) acc[mf][nf] = (f32x4){0.f, 0.f, 0.f, 0.f};

#define STAGE_A(BUF, HP, KK, DY, DX, CH)                                     \
  gload16(xpt + ((HP + DY) * 130 + DX) * 128 + (CH) * 64 + (KK) * 32,        \
          lds + (BUF) * 16384 + (HP) * 8192 + (KK) * 4096 + wvoff)
#define STAGE_B(BUF, HN, KK, TAP, CH)                                        \
  gload16(wpt + (size_t)(HN) * 147456 + (TAP) * 128 + (CH) * 64 + (KK) * 32, \
          lds + 32768 + (BUF) * 16384 + (HN) * 8192 + (KK) * 4096 + wvoff)

#define VMW4 asm volatile("s_waitcnt vmcnt(4)" ::: "memory")
#define VMW0 asm volatile("s_waitcnt vmcnt(0)" ::: "memory")
#define SCH0 __builtin_amdgcn_sched_barrier(0)
#define SP1 __builtin_amdgcn_s_setprio(1)
#define SP0 __builtin_amdgcn_s_setprio(0)

#define RD4(DST, BASE, OFF)                                                  \
  _Pragma("unroll") for (int i_ = 0; i_ < 4; ++i_)                           \
      DST[i_] = *(const short8*)((BASE) + (OFF) + i_ * 512)

#define MFMA16(BASE, AF, BF)                                                 \
  SP1;                                                                       \
  _Pragma("unroll") for (int q_ = 0; q_ < 4; ++q_)                           \
      _Pragma("unroll") for (int n_ = 0; n_ < 4; ++n_)                       \
          acc[(BASE) + q_][n_] = __builtin_amdgcn_mfma_f32_16x16x32_bf16(    \
              AF[q_], BF[n_], acc[(BASE) + q_][n_], 0, 0, 0);                \
  SP0

  short8 pra[4], prb[4];  // grp1: pre-read kk0 {af-mh0, bf} of current tile

  // ---- prologue: stage t0.kk0, t0.kk1, t1.kk0 (12 gloads)
  STAGE_A(0, 0, 0, 0, 0, 0);
  STAGE_A(0, 1, 0, 0, 0, 0);
  STAGE_B(0, 0, 0, 0, 0);
  STAGE_B(0, 1, 0, 0, 0);
  STAGE_A(0, 0, 1, 0, 0, 0);
  STAGE_A(0, 1, 1, 0, 0, 0);
  STAGE_B(0, 0, 1, 0, 0);
  STAGE_B(0, 1, 1, 0, 0);
  STAGE_A(1, 0, 0, 0, 0, 1);  // tile1 = tap0, ch1
  STAGE_A(1, 1, 0, 0, 0, 1);
  STAGE_B(1, 0, 0, 0, 1);
  STAGE_B(1, 1, 0, 0, 1);
  VMW4;  // forces t0.kk0 + t0.kk1 (8 oldest of 12)
  SCH0;
  __builtin_amdgcn_s_barrier();
  SCH0;
  if (grp) {  // seed anti-phase: pre-read tile0 kk0 {af-mh0, bf}
    RD4(pra, lds + aRd, 0);
    RD4(prb, lds + bRd, 0);
  }

#pragma unroll 1
  for (int kt = 0; kt < 18; ++kt) {
    const int buf_ = kt & 1;
    const int nb_ = buf_ ^ 1;
    const bool st1 = kt < 17;
    const bool st2 = kt < 16;
    const int t1_ = kt + 1, tap1 = t1_ >> 1, ch1 = t1_ & 1;
    const int dy1 = tap1 / 3, dx1 = tap1 - dy1 * 3;
    const int t2_ = kt + 2, tap2 = t2_ >> 1, ch2 = t2_ & 1;
    const int dy2 = tap2 / 3, dx2 = tap2 - dy2 * 3;
    const unsigned short* pA = lds + buf_ * 16384 + aRd;
    const unsigned short* pB = lds + buf_ * 16384 + bRd;
    const unsigned short* pAn = lds + nb_ * 16384 + aRd;
    const unsigned short* pBn = lds + nb_ * 16384 + bRd;
    short8 afx[4], afy[4], bfx[4], ua[4], ub[4];

    // ===== W1: kk0 compute; stage (kt+1).kk1
    if (st1) {
      STAGE_A(nb_, 0, 1, dy1, dx1, ch1);
      STAGE_A(nb_, 1, 1, dy1, dx1, ch1);
      STAGE_B(nb_, 0, 1, tap1, ch1);
      STAGE_B(nb_, 1, 1, tap1, ch1);
    }
    if (grp == 0) {  // read-first
      RD4(afx, pA, 0);
      RD4(bfx, pB, 0);
      MFMA16(0, afx, bfx);
      RD4(afy, pA, 2048);
      MFMA16(4, afy, bfx);
    } else {  // mfma-first on pre-read frags
      MFMA16(0, pra, prb);
      RD4(afy, pA, 2048);
      MFMA16(4, afy, prb);
      RD4(ua, pA, 4096);  // kk1 set for W2
      RD4(ub, pB, 4096);
    }
    if (st1) { VMW4; } else { VMW0; }  // forces (kt+1).kk0
    SCH0;
    __builtin_amdgcn_s_barrier();
    SCH0;

    // ===== W2: kk1 compute; stage (kt+2).kk0
    if (st2) {
      STAGE_A(buf_, 0, 0, dy2, dx2, ch2);
      STAGE_A(buf_, 1, 0, dy2, dx2, ch2);
      STAGE_B(buf_, 0, 0, tap2, ch2);
      STAGE_B(buf_, 1, 0, tap2, ch2);
    }
    if (grp == 0) {
      RD4(afx, pA, 4096);
      RD4(bfx, pB, 4096);
      MFMA16(0, afx, bfx);
      RD4(afy, pA, 6144);
      MFMA16(4, afy, bfx);
    } else {
      MFMA16(0, ua, ub);
      RD4(afy, pA, 6144);
      MFMA16(4, afy, ub);
      if (st1) {  // pre-read next tile kk0 {af-mh0, bf} (landed: mid VMW+bar)
        RD4(pra, pAn, 0);
        RD4(prb, pBn, 0);
      }
    }
    if (st2) { VMW4; } else { VMW0; }  // forces (kt+1).kk1
    SCH0;
    __builtin_amdgcn_s_barrier();
    SCH0;
  }

#undef MFMA16
#undef RD4
#undef STAGE_A
#undef STAGE_B

  // ---- epilogue: max over 8 rotations (8 adjacent n' cols), coalesced store
  float* lE = (float*)lds;  // [256 pix][33] fp32
#pragma unroll
  for (int mf = 0; mf < 8; ++mf)
#pragma unroll
    for (int nf = 0; nf < 4; ++nf)
#pragma unroll
      for (int j = 0; j < 4; ++j) {
        float v = acc[mf][nf][j];
        v = fmaxf(v, __shfl_xor(v, 1, 64));
        v = fmaxf(v, __shfl_xor(v, 2, 64));
        v = fmaxf(v, __shfl_xor(v, 4, 64));
        if ((lane & 7) == 0) {
          int pix = wr * 128 + mf * 16 + lhi * 4 + j;
          int ol = wc * 8 + nf * 2 + ((lane >> 3) & 1);
          lE[pix * 33 + ol] = v;
        }
      }
  __syncthreads();
  const size_t obase = ((size_t)(b * 128 + nblk * 32) * 128 + y0) * 128;
#pragma unroll
  for (int i = 0; i < 16; ++i) {
    int idx = i * 512 + tid;
    int ol = idx >> 8;
    int pix = idx & 255;
    int yl = pix >> 7;
    int xx = pix & 127;
    out[obase + (size_t)ol * 16384 + yl * 128 + xx] = lE[pix * 33 + ol];
  }
}

extern "C" void kernel_launch(void* const* d_in, const int* in_sizes, int n_in,
                              void* d_out, int out_size, void* d_ws, size_t ws_size,
                              hipStream_t stream) {
  const float* x = (const float*)d_in[0];
  const float* w = (const float*)d_in[1];
  const float* ra = (const float*)d_in[2];
  float* out = (float*)d_out;
  unsigned short* xp = (unsigned short*)d_ws;
  unsigned short* w2 = (unsigned short*)((char*)d_ws + XP_BYTES);

  hipLaunchKernelGGL(wprep_kernel, dim3(512), dim3(256), 0, stream, w, ra, w2);
  hipLaunchKernelGGL(xprep_kernel, dim3(130, 16), dim3(256), 0, stream, x, xp);
  hipLaunchKernelGGL(conv_kernel, dim3(4096), dim3(512), 0, stream, xp, w2, out);
}

// Round 8
// 812.075 us; speedup vs baseline: 4.1748x; 4.1748x over previous
//
#include <hip/hip_runtime.h>

typedef short short8 __attribute__((ext_vector_type(8)));
typedef float f32x4 __attribute__((ext_vector_type(4)));

#define XP_BYTES (16ull * 130 * 130 * 128 * 2)

static __device__ __forceinline__ unsigned short f2bf(float f) {
  unsigned u = __float_as_uint(f);
  u += 0x7FFFu + ((u >> 16) & 1u);
  return (unsigned short)(u >> 16);
}

static __device__ __forceinline__ void gload16(const void* g, void* l) {
  __builtin_amdgcn_global_load_lds(
      (const __attribute__((address_space(1))) void*)g,
      (__attribute__((address_space(3))) void*)l, 16, 0, 0);
}

// ---------------- weight rotation: (O*R,I,3,3) fp32 -> W2[n'=o*8+r][tap*128+ic] bf16
static __device__ __forceinline__ float wtap(const float* f, int yi, int xi) {
  bool valid = (yi >= 0) & (yi < 3) & (xi >= 0) & (xi < 3);
  int yc = min(max(yi, 0), 2), xc = min(max(xi, 0), 2);
  return valid ? f[yc * 3 + xc] : 0.f;
}

__global__ __launch_bounds__(256) void wprep_kernel(
    const float* __restrict__ w, const float* __restrict__ rot_alpha,
    unsigned short* __restrict__ w2) {
  int gid = blockIdx.x * 256 + threadIdx.x;  // 131072 = 1024 * 128
  int ic = gid & 127;
  int nr = gid >> 7;  // n' = o*8 + r
  int r = nr & 7;
  const float* wf = w + (size_t)nr * (128 * 9) + (size_t)ic * 9;
  float f[9];
#pragma unroll
  for (int q = 0; q < 9; ++q) f[q] = wf[q];
  float ang = rot_alpha[r] * 0.78539816339744830962f * (float)r;
  float sth, cth;
  sincosf(ang, &sth, &cth);
#pragma unroll
  for (int j = 0; j < 3; ++j) {
#pragma unroll
    for (int i = 0; i < 3; ++i) {
      float gy = (float)(j - 1), gx = (float)(i - 1);
      float xs = cth * gx - sth * gy;
      float ys = sth * gx + cth * gy;
      float ix = xs + 1.0f, iy = ys + 1.0f;
      float x0f = floorf(ix), y0f = floorf(iy);
      int x0 = (int)x0f, y0 = (int)y0f;
      float wx = ix - x0f, wy = iy - y0f;
      float acc = wtap(f, y0, x0) * (1.f - wy) * (1.f - wx)
                + wtap(f, y0, x0 + 1) * (1.f - wy) * wx
                + wtap(f, y0 + 1, x0) * wy * (1.f - wx)
                + wtap(f, y0 + 1, x0 + 1) * wy * wx;
      w2[(size_t)nr * 1152 + (size_t)(j * 3 + i) * 128 + ic] = f2bf(acc);
    }
  }
}

// ---------------- x: NCHW fp32 -> padded NHWC bf16 xp[16][130][130][128]
__global__ __launch_bounds__(256) void xprep_kernel(
    const float* __restrict__ x, unsigned short* __restrict__ xp) {
  const int yy = blockIdx.x;  // 0..129
  const int b = blockIdx.y;   // 0..15
  const int t = threadIdx.x;
  const size_t rowbase = ((size_t)b * 130 + yy) * (130 * 128);
  if (yy == 0 || yy == 129) {
    uint4 z = {0u, 0u, 0u, 0u};
    for (int i = t; i < 2080; i += 256)
      ((uint4*)(xp + rowbase))[i] = z;
    return;
  }
  const int y = yy - 1;
  __shared__ float lt[32][129];
  if (t < 32) {
    uint4 z = {0u, 0u, 0u, 0u};
    int xx = (t < 16) ? 0 : 129;
    int cc = (t & 15) * 8;
    *(uint4*)(xp + rowbase + (size_t)xx * 128 + cc) = z;
  }
  for (int c0 = 0; c0 < 128; c0 += 32) {
#pragma unroll
    for (int i = 0; i < 16; ++i) {
      int idx = i * 256 + t;
      int c = idx >> 7, wq = idx & 127;
      lt[c][wq] = x[(((size_t)b * 128 + c0 + c) * 128 + y) * 128 + wq];
    }
    __syncthreads();
#pragma unroll
    for (int i = 0; i < 2; ++i) {
      int u = i * 256 + t;
      int xx = u >> 2, cp = (u & 3) * 8;
      unsigned short v[8];
#pragma unroll
      for (int q = 0; q < 8; ++q) v[q] = f2bf(lt[cp + q][xx]);
      *(uint4*)(xp + rowbase + (size_t)(xx + 1) * 128 + c0 + cp) = *(uint4*)v;
    }
    __syncthreads();
  }
}

// ---------------- implicit-GEMM conv, 128x128 tile, BK=64, 4 waves, 64 KiB LDS
// -> 2 INDEPENDENT blocks per CU (separate barrier domains) so one block's
// LDS read-burst overlaps the other's MFMA cluster. Deep half-tile staging:
// P0 stages (kt+1).kk1, P1 stages (kt+2).kk0; steady-state vmcnt(8).
// LDS: A[2buf][2kk][128 row][32k] + B same = 64 KiB, XOR-swizzled slots.
__global__ __launch_bounds__(256, 2) void conv_kernel(
    const unsigned short* __restrict__ xp,
    const unsigned short* __restrict__ w2,
    float* __restrict__ out) {
  __shared__ unsigned short lds[32768];  // 64 KiB

  const int tid = threadIdx.x;
  const int lane = tid & 63;
  const int wv = tid >> 6;  // 0..3
  const int wr = wv >> 1;   // M half (64 rows)
  const int wc = wv & 1;    // N half (64 n')

  const int bid = blockIdx.x;
  const int wg = (bid & 7) * 2048 + (bid >> 3);  // XCD swizzle (16384 % 8 == 0)
  const int mblk = wg >> 3;  // 0..2047 : 8 consecutive wg share the A panel
  const int nblk = wg & 7;   // 0..7
  const int b = mblk >> 7;
  const int y = mblk & 127;

  // staging decode: thread t covers row r0 (0..63), lds slot s0 (16B, 4/row)
  const int r0 = tid >> 2;
  const int s0 = tid & 3;
  const int g0 = s0 ^ ((r0 >> 1) & 3);  // global k-group (inverse swizzle)

  const unsigned short* xpt =
      xp + (size_t)(b * 130 + y) * 130 * 128 + r0 * 128 + g0 * 8;
  const unsigned short* wpt =
      w2 + (size_t)nblk * 128 * 1152 + (size_t)r0 * 1152 + g0 * 8;

  const int l15 = lane & 15;
  const int lhi = lane >> 4;
  const int sa = (lhi ^ ((l15 >> 1) & 3)) * 8;  // read-side swizzled slot

  const int aRd = wr * 2048 + l15 * 32 + sa;           // shorts (within buf)
  const int bRd = 16384 + wc * 2048 + l15 * 32 + sa;

  f32x4 acc[4][4];
#pragma unroll
  for (int mf = 0; mf < 4; ++mf)
#pragma unroll
    for (int nf = 0; nf < 4; ++nf) acc[mf][nf] = (f32x4){0.f, 0.f, 0.f, 0.f};

  // A region per buf: [2 kk][2 half][64 row][32k] ; half = rows 0-63 / 64-127
#define STAGE_A(BUF, HALF, KK, DY, DX, CH)                                    \
  gload16(xpt + ((DY) * 130 + (HALF) * 64 + (DX)) * 128 + (CH) * 64 + (KK) * 32, \
          lds + (BUF) * 8192 + (KK) * 4096 + (HALF) * 2048 + wv * 512)
#define STAGE_B(BUF, HALF, KK, TAP, CH)                                       \
  gload16(wpt + (size_t)(HALF) * 64 * 1152 + (TAP) * 128 + (CH) * 64 + (KK) * 32, \
          lds + 16384 + (BUF) * 8192 + (KK) * 4096 + (HALF) * 2048 + wv * 512)

#define VMW(n) asm volatile("s_waitcnt vmcnt(" #n ")" ::: "memory")
#define LGKM0 asm volatile("s_waitcnt lgkmcnt(0)" ::: "memory")
#define SCH0 __builtin_amdgcn_sched_barrier(0)

  // stage one kk-half of K-tile T (tap=T>>1, ch=T&1) into BUF : 4 gloads
#define STAGE_HALF(BUF, KK, T)                                                \
  {                                                                           \
    const int tp_ = (T) >> 1, c_ = (T) & 1;                                   \
    const int dy_ = tp_ / 3, dx_ = tp_ - dy_ * 3;                             \
    STAGE_A(BUF, 0, KK, dy_, dx_, c_);                                        \
    STAGE_A(BUF, 1, KK, dy_, dx_, c_);                                        \
    STAGE_B(BUF, 0, KK, tp_, c_);                                             \
    STAGE_B(BUF, 1, KK, tp_, c_);                                             \
  }

#define PHASE(BUF, KK, STG, VMX)                                              \
  {                                                                           \
    const unsigned short* pA_ = lds + (BUF) * 8192 + (KK) * 4096 + aRd;       \
    const unsigned short* pB_ = lds + (BUF) * 8192 + (KK) * 4096 + bRd;       \
    short8 af[4], bf[4];                                                      \
    _Pragma("unroll") for (int q = 0; q < 4; ++q)                             \
        af[q] = *(const short8*)(pA_ + q * 512);                              \
    _Pragma("unroll") for (int n = 0; n < 4; ++n)                             \
        bf[n] = *(const short8*)(pB_ + n * 512);                              \
    STG;                                                                      \
    SCH0;                                                                     \
    __builtin_amdgcn_s_barrier();                                             \
    LGKM0;                                                                    \
    __builtin_amdgcn_s_setprio(1);                                            \
    _Pragma("unroll") for (int q = 0; q < 4; ++q)                             \
        _Pragma("unroll") for (int n = 0; n < 4; ++n)                         \
            acc[q][n] = __builtin_amdgcn_mfma_f32_16x16x32_bf16(              \
                af[q], bf[n], acc[q][n], 0, 0, 0);                            \
    __builtin_amdgcn_s_setprio(0);                                            \
    VMX;                                                                      \
    __builtin_amdgcn_s_barrier();                                             \
  }

  // ---- prologue: stage t0.kk0, t0.kk1, t1.kk0 (12 gloads); force t0.kk0
  STAGE_HALF(0, 0, 0);
  STAGE_HALF(0, 1, 0);
  STAGE_HALF(1, 0, 1);
  VMW(8);
  SCH0;
  __builtin_amdgcn_s_barrier();

#pragma unroll 1
  for (int kt = 0; kt < 16; ++kt) {
    const int buf_ = kt & 1;
    // P0: compute kk0; stage (kt+1).kk1 ; force kt.kk1
    PHASE(buf_, 0, STAGE_HALF(buf_ ^ 1, 1, kt + 1), VMW(8));
    // P1: compute kk1; stage (kt+2).kk0 (same buf, kk0 region) ; force (kt+1).kk0
    PHASE(buf_, 1, STAGE_HALF(buf_, 0, kt + 2), VMW(8));
  }
  // kt = 16
  PHASE(0, 0, STAGE_HALF(1, 1, 17), VMW(8));
  PHASE(0, 1, , VMW(4));
  // kt = 17
  PHASE(1, 0, , VMW(0));
  PHASE(1, 1, , VMW(0));

#undef PHASE
#undef STAGE_HALF
#undef STAGE_A
#undef STAGE_B

  // ---- epilogue: max over 8 rotations (8 adjacent n' cols), coalesced store
  float* lE = (float*)lds;  // [128 pix][17] fp32
#pragma unroll
  for (int mf = 0; mf < 4; ++mf)
#pragma unroll
    for (int nf = 0; nf < 4; ++nf)
#pragma unroll
      for (int j = 0; j < 4; ++j) {
        float v = acc[mf][nf][j];
        v = fmaxf(v, __shfl_xor(v, 1, 64));
        v = fmaxf(v, __shfl_xor(v, 2, 64));
        v = fmaxf(v, __shfl_xor(v, 4, 64));
        if ((lane & 7) == 0) {
          int pix = wr * 64 + mf * 16 + lhi * 4 + j;
          int ol = wc * 8 + nf * 2 + ((lane >> 3) & 1);
          lE[pix * 17 + ol] = v;
        }
      }
  __syncthreads();
  const size_t obase = ((size_t)(b * 128 + nblk * 16) * 128 + y) * 128;
#pragma unroll
  for (int i = 0; i < 8; ++i) {
    int idx = i * 256 + tid;
    int ol = idx >> 7;   // 0..15
    int xx = idx & 127;
    out[obase + (size_t)ol * 16384 + xx] = lE[xx * 17 + ol];
  }
}

extern "C" void kernel_launch(void* const* d_in, const int* in_sizes, int n_in,
                              void* d_out, int out_size, void* d_ws, size_t ws_size,
                              hipStream_t stream) {
  const float* x = (const float*)d_in[0];
  const float* w = (const float*)d_in[1];
  const float* ra = (const float*)d_in[2];
  float* out = (float*)d_out;
  unsigned short* xp = (unsigned short*)d_ws;
  unsigned short* w2 = (unsigned short*)((char*)d_ws + XP_BYTES);

  hipLaunchKernelGGL(wprep_kernel, dim3(512), dim3(256), 0, stream, w, ra, w2);
  hipLaunchKernelGGL(xprep_kernel, dim3(130, 16), dim3(256), 0, stream, x, xp);
  hipLaunchKernelGGL(conv_kernel, dim3(16384), dim3(256), 0, stream, xp, w2, out);
}